// Round 2
// baseline (1486.223 us; speedup 1.0000x reference)
//
#include <hip/hip_runtime.h>

#define NB 16     // nodes per graph
#define FI 64     // input features
#define FH 128    // hidden/output features

__global__ __launch_bounds__(256) void scatter_flags(const int* __restrict__ e,
                                                     unsigned char* __restrict__ fl,
                                                     int n) {
    int i = blockIdx.x * 256 + threadIdx.x;
    if (i < n) fl[e[i]] = 1;
}

__global__ __launch_bounds__(256) void sage_fused(
    const float* __restrict__ x,               // [B*16, 64] f32
    const unsigned char* __restrict__ flags,   // [B*16]
    const float* __restrict__ adjp,            // [16,16]
    const float* __restrict__ Wr1,             // [64,128]
    const float* __restrict__ br1,             // [128]
    const float* __restrict__ Wo1,             // [64,128]
    const float* __restrict__ Wr2,             // [128,128]
    const float* __restrict__ br2,             // [128]
    const float* __restrict__ Wo2,             // [128,128]
    float* __restrict__ out)                   // [B*16,128] f32
{
    __shared__ float s_w[NB][NB];     // t_i * t_j * adj[i][j] / deg_i
    __shared__ float s_t[NB];
    __shared__ float s_inv[NB];
    __shared__ float s_x[NB][FI];
    __shared__ float s_a1[NB][FI];    // (adj@x)/deg
    __shared__ float s_h[NB][FH];     // relu(layer1)
    __shared__ float s_a2[NB][FH];    // (adj@h)/deg

    const int b = blockIdx.x;
    const int tid = threadIdx.x;

    if (tid < NB) s_t[tid] = flags[b * NB + tid] ? 1.0f : 0.0f;
    __syncthreads();

    // deg_i = max(t_i * sum_j adj[i][j]*t_j, 1)
    if (tid < NB) {
        float s = 0.f;
        #pragma unroll
        for (int j = 0; j < NB; ++j) s += adjp[tid * NB + j] * s_t[j];
        s *= s_t[tid];
        s_inv[tid] = 1.0f / fmaxf(s, 1.0f);
    }
    // stage x: 1024 floats, one float4 per thread
    {
        const float4* xp = (const float4*)(x + (size_t)b * (NB * FI));
        float4 v = xp[tid];
        int e = tid * 4; int i = e >> 6; int f = e & 63;
        *(float4*)&s_x[i][f] = v;
    }
    __syncthreads();

    {
        int i = tid >> 4, j = tid & 15;
        s_w[i][j] = s_t[i] * s_t[j] * adjp[i * NB + j] * s_inv[i];
    }
    __syncthreads();

    // a1[i][f] = sum_j w[i][j] * x[j][f]
    {
        int e = tid * 4; int i = e >> 6; int f = e & 63;
        float4 acc = make_float4(0.f, 0.f, 0.f, 0.f);
        #pragma unroll
        for (int j = 0; j < NB; ++j) {
            float wj = s_w[i][j];
            float4 xv = *(const float4*)&s_x[j][f];
            acc.x += wj * xv.x; acc.y += wj * xv.y;
            acc.z += wj * xv.z; acc.w += wj * xv.w;
        }
        *(float4*)&s_a1[i][f] = acc;
    }
    __syncthreads();

    const int o  = tid & 127;
    const int iB = (tid >> 7) * 8;

    // layer 1: h = relu(a1 @ Wr1 + br1 + x @ Wo1)
    {
        float acc[8];
        float bb = br1[o];
        #pragma unroll
        for (int r = 0; r < 8; ++r) acc[r] = bb;
        for (int f = 0; f < FI; f += 4) {
            float wr[4], wo[4];
            #pragma unroll
            for (int q = 0; q < 4; ++q) {
                wr[q] = Wr1[(f + q) * FH + o];
                wo[q] = Wo1[(f + q) * FH + o];
            }
            #pragma unroll
            for (int r = 0; r < 8; ++r) {
                float4 a  = *(const float4*)&s_a1[iB + r][f];
                float4 xx = *(const float4*)&s_x[iB + r][f];
                acc[r] += a.x * wr[0] + a.y * wr[1] + a.z * wr[2] + a.w * wr[3];
                acc[r] += xx.x * wo[0] + xx.y * wo[1] + xx.z * wo[2] + xx.w * wo[3];
            }
        }
        #pragma unroll
        for (int r = 0; r < 8; ++r) s_h[iB + r][o] = fmaxf(acc[r], 0.0f);
    }
    __syncthreads();

    // a2[i][f] = sum_j w[i][j] * h[j][f]
    {
        int e = tid * 8; int i = e >> 7; int f = e & 127;
        float4 acc0 = make_float4(0.f, 0.f, 0.f, 0.f);
        float4 acc1 = make_float4(0.f, 0.f, 0.f, 0.f);
        #pragma unroll
        for (int j = 0; j < NB; ++j) {
            float wj = s_w[i][j];
            float4 h0 = *(const float4*)&s_h[j][f];
            float4 h1 = *(const float4*)&s_h[j][f + 4];
            acc0.x += wj * h0.x; acc0.y += wj * h0.y;
            acc0.z += wj * h0.z; acc0.w += wj * h0.w;
            acc1.x += wj * h1.x; acc1.y += wj * h1.y;
            acc1.z += wj * h1.z; acc1.w += wj * h1.w;
        }
        *(float4*)&s_a2[i][f]     = acc0;
        *(float4*)&s_a2[i][f + 4] = acc1;
    }
    __syncthreads();

    // layer 2: out = a2 @ Wr2 + br2 + h @ Wo2
    {
        float acc[8];
        float bb = br2[o];
        #pragma unroll
        for (int r = 0; r < 8; ++r) acc[r] = bb;
        for (int f = 0; f < FH; f += 4) {
            float wr[4], wo[4];
            #pragma unroll
            for (int q = 0; q < 4; ++q) {
                wr[q] = Wr2[(f + q) * FH + o];
                wo[q] = Wo2[(f + q) * FH + o];
            }
            #pragma unroll
            for (int r = 0; r < 8; ++r) {
                float4 a  = *(const float4*)&s_a2[iB + r][f];
                float4 hh = *(const float4*)&s_h[iB + r][f];
                acc[r] += a.x * wr[0] + a.y * wr[1] + a.z * wr[2] + a.w * wr[3];
                acc[r] += hh.x * wo[0] + hh.y * wo[1] + hh.z * wo[2] + hh.w * wo[3];
            }
        }
        float* op = out + ((size_t)b * NB + iB) * FH + o;
        #pragma unroll
        for (int r = 0; r < 8; ++r) op[r * FH] = acc[r];
    }
}

extern "C" void kernel_launch(void* const* d_in, const int* in_sizes, int n_in,
                              void* d_out, int out_size, void* d_ws, size_t ws_size,
                              hipStream_t stream) {
    const float* x    = (const float*)d_in[0];
    const int*   edge = (const int*)d_in[1];
    const float* adjp = (const float*)d_in[2];
    const float* Wr1  = (const float*)d_in[3];
    const float* br1  = (const float*)d_in[4];
    const float* Wo1  = (const float*)d_in[5];
    const float* Wr2  = (const float*)d_in[6];
    const float* br2  = (const float*)d_in[7];
    const float* Wo2  = (const float*)d_in[8];
    float* out = (float*)d_out;

    const int total_nodes = in_sizes[0] / FI;      // B*N = 524288
    const int batches     = total_nodes / NB;      // 32768
    const int nedge       = in_sizes[1];           // 262144

    unsigned char* flags = (unsigned char*)d_ws;
    hipMemsetAsync(flags, 0, (size_t)total_nodes, stream);
    scatter_flags<<<(nedge + 255) / 256, 256, 0, stream>>>(edge, flags, nedge);
    sage_fused<<<batches, 256, 0, stream>>>(x, flags, adjp, Wr1, br1, Wo1,
                                            Wr2, br2, Wo2, out);
}

// Round 3
// 452.213 us; speedup vs baseline: 3.2866x; 3.2866x over previous
//
#include <hip/hip_runtime.h>

typedef unsigned short u16;
typedef float floatx4 __attribute__((ext_vector_type(4)));
typedef short shortx8 __attribute__((ext_vector_type(8)));

#define MFMA16(a, b, c) __builtin_amdgcn_mfma_f32_16x16x32_bf16(a, b, c, 0, 0, 0)

__device__ __forceinline__ u16 f2b(float f) {
    union { float f; unsigned u; } c;
    c.f = f;
    unsigned lsb = (c.u >> 16) & 1u;
    c.u += 0x7fffu + lsb;           // round-to-nearest-even
    return (u16)(c.u >> 16);
}

__global__ __launch_bounds__(256) void scatter_flags(const int* __restrict__ e,
                                                     unsigned char* __restrict__ fl,
                                                     int n) {
    int i = blockIdx.x * 256 + threadIdx.x;
    if (i < n) fl[e[i]] = 1;
}

// Convert weights fp32 [K][N] -> bf16 transposed [N][K] (B-fragment friendly).
__global__ __launch_bounds__(256) void prep_weights(
    const float* __restrict__ W1r, const float* __restrict__ W1o,
    const float* __restrict__ W2r, const float* __restrict__ W2o,
    u16* __restrict__ W1rt, u16* __restrict__ W1ot,
    u16* __restrict__ W2rt, u16* __restrict__ W2ot)
{
    int t = blockIdx.x * 256 + threadIdx.x;
    union { u16 h[4]; unsigned long long ll; } pk;
    if (t < 2048) {                       // W1r: [64][128] -> [128][64]
        int n = t >> 4, k0 = (t & 15) * 4;
        #pragma unroll
        for (int j = 0; j < 4; ++j) pk.h[j] = f2b(W1r[(k0 + j) * 128 + n]);
        *(unsigned long long*)(W1rt + n * 64 + k0) = pk.ll;
    } else if (t < 4096) {                // W1o
        int tt = t - 2048; int n = tt >> 4, k0 = (tt & 15) * 4;
        #pragma unroll
        for (int j = 0; j < 4; ++j) pk.h[j] = f2b(W1o[(k0 + j) * 128 + n]);
        *(unsigned long long*)(W1ot + n * 64 + k0) = pk.ll;
    } else if (t < 8192) {                // W2r: [128][128] -> [128][128]
        int tt = t - 4096; int n = tt >> 5, k0 = (tt & 31) * 4;
        #pragma unroll
        for (int j = 0; j < 4; ++j) pk.h[j] = f2b(W2r[(k0 + j) * 128 + n]);
        *(unsigned long long*)(W2rt + n * 128 + k0) = pk.ll;
    } else if (t < 12288) {               // W2o
        int tt = t - 8192; int n = tt >> 5, k0 = (tt & 31) * 4;
        #pragma unroll
        for (int j = 0; j < 4; ++j) pk.h[j] = f2b(W2o[(k0 + j) * 128 + n]);
        *(unsigned long long*)(W2ot + n * 128 + k0) = pk.ll;
    }
}

// One block = 4 graphs (M=64 rows), 4 waves. Wave w owns output cols tn in {2w, 2w+1}.
__global__ __launch_bounds__(256, 3) void sage_mfma(
    const float* __restrict__ x,               // [B*16, 64] f32
    const unsigned char* __restrict__ flags,   // [B*16]
    const float* __restrict__ adjp,            // [16,16] f32
    const float* __restrict__ br1,             // [128] f32
    const float* __restrict__ br2,             // [128] f32
    const u16* __restrict__ W1rt,              // [128][64] bf16 (transposed)
    const u16* __restrict__ W1ot,              // [128][64]
    const u16* __restrict__ W2rt,              // [128][128]
    const u16* __restrict__ W2ot,              // [128][128]
    float* __restrict__ out)                   // [B*16,128] f32
{
    // LDS carve (44544 B -> 3 blocks/CU):
    __shared__ __align__(16) unsigned char smem[44544];
    u16*   s_w    = (u16*)smem;                 // [4][16][32] wbar, K-padded w/ zeros
    float* s_flag = (float*)(smem + 4096);      // [64]
    float* s_inv  = (float*)(smem + 4352);      // [64]
    u16*   s_t    = (u16*)(smem + 4608);        // [128][88] y1^T / u1^T (f-major)
    u16*   s_x    = (u16*)(smem + 27136);       // [64][72] bf16 x     (phase A)
    u16*   s_h    = (u16*)(smem + 27136);       // [64][136] bf16 h    (phase C) — overlaps s_x

    const int b   = blockIdx.x;
    const int tid = threadIdx.x;
    const int w   = tid >> 6;
    const int l   = tid & 63;
    const int q   = l >> 4;
    const int lr  = l & 15;
    const int tn0 = 2 * w;
    const floatx4 fz = {0.f, 0.f, 0.f, 0.f};

    // zero s_t: pad cols must be 0 so zero-padded wbar K never hits NaN garbage
    {
        uint4 z = {0, 0, 0, 0};
        uint4* tz = (uint4*)s_t;               // 22528 B = 1408 uint4
        #pragma unroll
        for (int i = 0; i < 6; ++i) { int idx = tid + i * 256; if (idx < 1408) tz[idx] = z; }
    }
    if (tid < 64) s_flag[tid] = flags[b * 64 + tid] ? 1.0f : 0.0f;
    // stage x -> bf16 LDS row-major [64][72]
    {
        const float4* xg = (const float4*)(x + (size_t)b * 4096);
        #pragma unroll
        for (int i = 0; i < 4; ++i) {
            int e = tid + i * 256;
            float4 v = xg[e];
            int row = e >> 4, f = (e & 15) * 4;
            union { u16 h[4]; unsigned long long ll; } pk;
            pk.h[0] = f2b(v.x); pk.h[1] = f2b(v.y); pk.h[2] = f2b(v.z); pk.h[3] = f2b(v.w);
            *(unsigned long long*)(s_x + row * 72 + f) = pk.ll;
        }
    }
    __syncthreads();
    if (tid < 64) {
        int g = tid >> 4, i = tid & 15;
        float s = 0.f;
        #pragma unroll
        for (int j = 0; j < 16; ++j) s += adjp[i * 16 + j] * s_flag[g * 16 + j];
        s *= s_flag[tid];
        s_inv[tid] = 1.0f / fmaxf(s, 1.0f);
    }
    __syncthreads();
    // build wbar bf16, A-operand layout [16][32] per graph, zero pad k>=16
    {
        int flat = tid * 8;
        int g = flat >> 9, rem = flat & 511, i = rem >> 5, k0 = rem & 31;
        float ti = s_flag[g * 16 + i] * s_inv[g * 16 + i];
        union { u16 h[8]; uint4 v; } pk;
        #pragma unroll
        for (int j = 0; j < 8; ++j) {
            int k = k0 + j;
            float val = (k < 16) ? ti * s_flag[g * 16 + k] * adjp[i * 16 + k] : 0.f;
            pk.h[j] = f2b(val);
        }
        *(uint4*)(s_w + g * 512 + i * 32 + k0) = pk.v;
    }
    // GEMM1 B-fragments from global (L2-hot) + biases
    shortx8 b1r[2][2], b1o[2][2];
    float bias1[2], bias2[2];
    #pragma unroll
    for (int tni = 0; tni < 2; ++tni) {
        int n = (tn0 + tni) * 16 + lr;
        bias1[tni] = br1[n]; bias2[tni] = br2[n];
        #pragma unroll
        for (int ks = 0; ks < 2; ++ks) {
            b1r[tni][ks] = *(const shortx8*)(W1rt + n * 64 + ks * 32 + q * 8);
            b1o[tni][ks] = *(const shortx8*)(W1ot + n * 64 + ks * 32 + q * 8);
        }
    }
    __syncthreads();

    // -------- Phase A: y1 = x@W1r -> s_t transposed; y2 = x@W1o stays in regs
    floatx4 y2acc[4][2];
    #pragma unroll
    for (int tm = 0; tm < 4; ++tm) {
        shortx8 ax[2];
        #pragma unroll
        for (int ks = 0; ks < 2; ++ks)
            ax[ks] = *(const shortx8*)(s_x + (tm * 16 + lr) * 72 + ks * 32 + q * 8);
        floatx4 y1[2] = {fz, fz};
        #pragma unroll
        for (int tni = 0; tni < 2; ++tni) {
            y2acc[tm][tni] = fz;
            #pragma unroll
            for (int ks = 0; ks < 2; ++ks) {
                y1[tni]        = MFMA16(ax[ks], b1r[tni][ks], y1[tni]);
                y2acc[tm][tni] = MFMA16(ax[ks], b1o[tni][ks], y2acc[tm][tni]);
            }
        }
        #pragma unroll
        for (int tni = 0; tni < 2; ++tni) {      // C-layout -> transposed b64 write
            union { u16 h[4]; unsigned long long ll; } pk;
            #pragma unroll
            for (int r = 0; r < 4; ++r) pk.h[r] = f2b(y1[tni][r]);
            *(unsigned long long*)(s_t + ((tn0 + tni) * 16 + lr) * 88 + tm * 16 + q * 4) = pk.ll;
        }
    }
    __syncthreads();

    // -------- Phase B: h = relu(wbar @ y1 + y2 + b1) -> s_h row-major bf16
    shortx8 wfrag[4];
    #pragma unroll
    for (int g = 0; g < 4; ++g)
        wfrag[g] = *(const shortx8*)(s_w + g * 512 + lr * 32 + q * 8);
    #pragma unroll
    for (int g = 0; g < 4; ++g) {
        #pragma unroll
        for (int tni = 0; tni < 2; ++tni) {
            shortx8 bf = *(const shortx8*)(s_t + ((tn0 + tni) * 16 + lr) * 88 + g * 16 + q * 8);
            floatx4 a = MFMA16(wfrag[g], bf, fz);
            #pragma unroll
            for (int r = 0; r < 4; ++r) {
                float hv = fmaxf(a[r] + y2acc[g][tni][r] + bias1[tni], 0.f);
                s_h[(g * 16 + q * 4 + r) * 136 + (tn0 + tni) * 16 + lr] = f2b(hv);
            }
        }
    }
    __syncthreads();

    // -------- Phase C: u1 = h@W2r -> s_t transposed; u2 = h@W2o stays in regs
    shortx8 b2r[2][4], b2o[2][4];
    #pragma unroll
    for (int tni = 0; tni < 2; ++tni) {
        int n = (tn0 + tni) * 16 + lr;
        #pragma unroll
        for (int ks = 0; ks < 4; ++ks) {
            b2r[tni][ks] = *(const shortx8*)(W2rt + n * 128 + ks * 32 + q * 8);
            b2o[tni][ks] = *(const shortx8*)(W2ot + n * 128 + ks * 32 + q * 8);
        }
    }
    floatx4 u2acc[4][2];
    #pragma unroll
    for (int tm = 0; tm < 4; ++tm) {
        shortx8 ah[4];
        #pragma unroll
        for (int ks = 0; ks < 4; ++ks)
            ah[ks] = *(const shortx8*)(s_h + (tm * 16 + lr) * 136 + ks * 32 + q * 8);
        floatx4 u1[2] = {fz, fz};
        #pragma unroll
        for (int tni = 0; tni < 2; ++tni) {
            u2acc[tm][tni] = fz;
            #pragma unroll
            for (int ks = 0; ks < 4; ++ks) {
                u1[tni]        = MFMA16(ah[ks], b2r[tni][ks], u1[tni]);
                u2acc[tm][tni] = MFMA16(ah[ks], b2o[tni][ks], u2acc[tm][tni]);
            }
        }
        #pragma unroll
        for (int tni = 0; tni < 2; ++tni) {
            union { u16 h[4]; unsigned long long ll; } pk;
            #pragma unroll
            for (int r = 0; r < 4; ++r) pk.h[r] = f2b(u1[tni][r]);
            *(unsigned long long*)(s_t + ((tn0 + tni) * 16 + lr) * 88 + tm * 16 + q * 4) = pk.ll;
        }
    }
    __syncthreads();

    // -------- Phase D: out = wbar @ u1 + u2 + b2 (fp32 global)
    #pragma unroll
    for (int g = 0; g < 4; ++g) {
        #pragma unroll
        for (int tni = 0; tni < 2; ++tni) {
            shortx8 bf = *(const shortx8*)(s_t + ((tn0 + tni) * 16 + lr) * 88 + g * 16 + q * 8);
            floatx4 a = MFMA16(wfrag[g], bf, fz);
            float* op = out + ((size_t)b * 64 + g * 16 + q * 4) * 128 + (tn0 + tni) * 16 + lr;
            #pragma unroll
            for (int r = 0; r < 4; ++r)
                op[r * 128] = a[r] + u2acc[g][tni][r] + bias2[tni];
        }
    }
}

extern "C" void kernel_launch(void* const* d_in, const int* in_sizes, int n_in,
                              void* d_out, int out_size, void* d_ws, size_t ws_size,
                              hipStream_t stream) {
    const float* x    = (const float*)d_in[0];
    const int*   edge = (const int*)d_in[1];
    const float* adjp = (const float*)d_in[2];
    const float* W1r  = (const float*)d_in[3];
    const float* br1  = (const float*)d_in[4];
    const float* W1o  = (const float*)d_in[5];
    const float* W2r  = (const float*)d_in[6];
    const float* br2  = (const float*)d_in[7];
    const float* W2o  = (const float*)d_in[8];
    float* out = (float*)d_out;

    const int total_nodes = in_sizes[0] / 64;      // 524288
    const int nedge       = in_sizes[1];           // 262144
    const int nblocks     = total_nodes / 64;      // 8192

    unsigned char* flags = (unsigned char*)d_ws;
    u16* wbase = (u16*)((char*)d_ws + 524288);
    u16* W1rt = wbase;            // 8192 u16
    u16* W1ot = wbase + 8192;
    u16* W2rt = wbase + 16384;    // 16384 u16
    u16* W2ot = wbase + 32768;

    hipMemsetAsync(flags, 0, (size_t)total_nodes, stream);
    scatter_flags<<<(nedge + 255) / 256, 256, 0, stream>>>(edge, flags, nedge);
    prep_weights<<<48, 256, 0, stream>>>(W1r, W1o, W2r, W2o, W1rt, W1ot, W2rt, W2ot);
    sage_mfma<<<nblocks, 256, 0, stream>>>(x, flags, adjp, br1, br2,
                                           W1rt, W1ot, W2rt, W2ot, out);
}